// Round 6
// baseline (238.489 us; speedup 1.0000x reference)
//
#include <hip/hip_runtime.h>
#include <math.h>

#define Bn 16
#define Cn 256
#define Ln 16384
#define Mn 64
#define LN_EPS 1e-5f
#define CHUNK 512
#define NCH (Ln / CHUNK)   // 32

typedef float v4f __attribute__((ext_vector_type(4)));
typedef unsigned short ushort_t;
typedef ushort_t ush8 __attribute__((ext_vector_type(8)));

__device__ inline ushort_t f2bf(float f) {        // RNE float->bf16
    unsigned u = __builtin_bit_cast(unsigned, f);
    u += 0x7FFFu + ((u >> 16) & 1u);
    return (ushort_t)(u >> 16);
}
__device__ inline float bf2f(ushort_t h) {
    unsigned u = ((unsigned)h) << 16;
    return __builtin_bit_cast(float, u);
}

// K1: logits + chunk-local softmax numerator (+ optional bf16 copy of x).
// grid (NCH, Bn) = 512 blocks, 256 threads (8 waves/CU); thread owns one float2 of l.
template<bool WXB>
__global__ void k_pass1(const float* __restrict__ x, const float* __restrict__ w_mask,
                        const float* __restrict__ b_mask,
                        float* __restrict__ e_ws, float* __restrict__ mz,
                        ushort_t* __restrict__ xb) {
    const int ch = blockIdx.x, b = blockIdx.y;
    const int t = threadIdx.x;   // 256
    const size_t xbase = (size_t)b * Cn * Ln + (size_t)ch * CHUNK;
    __shared__ float wm[Cn];
    __shared__ float red[8];
    wm[t] = w_mask[t];
    __syncthreads();

    float2 acc = make_float2(0.f, 0.f);
    const float* xp = x + xbase + 2 * t;
    #pragma unroll 8
    for (int c = 0; c < Cn; ++c) {
        float2 v = *(const float2*)(xp + (size_t)c * Ln);
        if (WXB) {
            unsigned pk = (unsigned)f2bf(v.x) | ((unsigned)f2bf(v.y) << 16);
            *(unsigned*)(xb + xbase + (size_t)c * Ln + 2 * t) = pk;
        }
        const float w = wm[c];
        acc.x += v.x * w; acc.y += v.y * w;
    }
    const float bm = b_mask[0];
    acc.x += bm; acc.y += bm;

    float lm = fmaxf(acc.x, acc.y);
    for (int off = 32; off; off >>= 1) lm = fmaxf(lm, __shfl_xor(lm, off, 64));
    if ((t & 63) == 0) red[t >> 6] = lm;
    __syncthreads();
    const float m = fmaxf(fmaxf(red[0], red[1]), fmaxf(red[2], red[3]));

    float2 ev;
    ev.x = expf(acc.x - m); ev.y = expf(acc.y - m);
    *(float2*)(e_ws + (size_t)b * Ln + ch * CHUNK + 2 * t) = ev;
    float lz = ev.x + ev.y;
    for (int off = 32; off; off >>= 1) lz += __shfl_xor(lz, off, 64);
    if ((t & 63) == 0) red[4 + (t >> 6)] = lz;
    __syncthreads();
    if (t == 0) {
        mz[(b * NCH + ch) * 2 + 0] = m;
        mz[(b * NCH + ch) * 2 + 1] = red[4] + red[5] + red[6] + red[7];
    }
}

// K_norm: e_ws[b][l] *= exp(m_ch - M)/Z  -> final softmax probs. grid Bn, 256 thr.
__global__ void k_norm(float* __restrict__ e_ws, const float* __restrict__ mz) {
    const int b = blockIdx.x;
    const int t = threadIdx.x;   // 256
    __shared__ float s_sc[NCH];
    if (t < 64) {
        float mj = (t < NCH) ? mz[(b * NCH + t) * 2 + 0] : -1e30f;
        float zj = (t < NCH) ? mz[(b * NCH + t) * 2 + 1] : 0.f;
        float M = mj;
        for (int off = 32; off; off >>= 1) M = fmaxf(M, __shfl_xor(M, off, 64));
        float w = zj * expf(mj - M);
        float Z = w;
        for (int off = 32; off; off >>= 1) Z += __shfl_xor(Z, off, 64);
        if (t < NCH) s_sc[t] = expf(mj - M) / Z;
    }
    __syncthreads();
    float4* p = (float4*)(e_ws + (size_t)b * Ln);
    #pragma unroll
    for (int j = 0; j < 16; ++j) {
        const int i = j * 256 + t;        // float4 idx; elem = 4i; chunk = (4i)/512 = i>>7
        float4 v = p[i];
        const float sc = s_sc[i >> 7];
        v.x *= sc; v.y *= sc; v.z *= sc; v.w *= sc;
        p[i] = v;
    }
}

// K2: ctx[b][c] = dot(x_row, p_row). grid Bn*Cn, 256 thr.
template<bool BF>
__global__ void k_ctx(const float* __restrict__ x, const ushort_t* __restrict__ xb,
                      const float* __restrict__ p, float* __restrict__ ctx) {
    const int bc = blockIdx.x;
    const int b = bc >> 8;
    const int t = threadIdx.x;   // 256
    const float4* prow = (const float4*)(p + (size_t)b * Ln);
    float acc = 0.f;
    if (BF) {
        const ush8* xrow = (const ush8*)(xb + (size_t)bc * Ln);
        #pragma unroll
        for (int j = 0; j < 8; ++j) {
            const int e8 = j * 256 + t;   // 8-elem group idx
            ush8 h = xrow[e8];
            float4 p0 = prow[e8 * 2], p1 = prow[e8 * 2 + 1];
            acc += bf2f(h[0]) * p0.x + bf2f(h[1]) * p0.y + bf2f(h[2]) * p0.z + bf2f(h[3]) * p0.w
                 + bf2f(h[4]) * p1.x + bf2f(h[5]) * p1.y + bf2f(h[6]) * p1.z + bf2f(h[7]) * p1.w;
        }
    } else {
        const float4* xrow = (const float4*)(x + (size_t)bc * Ln);
        #pragma unroll
        for (int j = 0; j < 16; ++j) {
            float4 v = xrow[j * 256 + t];
            float4 w = prow[j * 256 + t];
            acc += v.x * w.x + v.y * w.y + v.z * w.z + v.w * w.w;
        }
    }
    for (int off = 32; off; off >>= 1) acc += __shfl_xor(acc, off, 64);
    __shared__ float red[4];
    if ((t & 63) == 0) red[t >> 6] = acc;
    __syncthreads();
    if (t == 0) ctx[bc] = red[0] + red[1] + red[2] + red[3];
}

// K3: tiny MLP on normalized ctx. grid Bn, 256 thr.
__global__ void k_mlp(const float* __restrict__ ctx, const float* __restrict__ w1,
                      const float* __restrict__ b1, const float* __restrict__ ln_g,
                      const float* __restrict__ ln_b, const float* __restrict__ w2,
                      const float* __restrict__ b2, float* __restrict__ add) {
    const int b = blockIdx.x;
    const int t = threadIdx.x;   // 256
    __shared__ float ctx_s[Cn];
    __shared__ float h_s[Mn];
    ctx_s[t] = ctx[b * Cn + t];
    __syncthreads();

    const int m4 = t >> 2, j = t & 3;
    float hp = 0.f;
    for (int c = j; c < Cn; c += 4) hp += ctx_s[c] * w1[m4 * Cn + c];
    hp += __shfl_xor(hp, 1, 64);
    hp += __shfl_xor(hp, 2, 64);
    if (j == 0) h_s[m4] = hp + b1[m4];
    __syncthreads();

    if (t < 64) {
        float h = h_s[t];
        float mu = h;
        for (int off = 32; off; off >>= 1) mu += __shfl_xor(mu, off, 64);
        mu *= (1.f / 64.f);
        const float d = h - mu;
        float var = d * d;
        for (int off = 32; off; off >>= 1) var += __shfl_xor(var, off, 64);
        var *= (1.f / 64.f);
        h = d * rsqrtf(var + LN_EPS) * ln_g[t] + ln_b[t];
        h_s[t] = fmaxf(h, 0.f);
    }
    __syncthreads();

    float a = b2[t];
    #pragma unroll
    for (int mm = 0; mm < Mn; ++mm) a += h_s[mm] * w2[t * Mn + mm];
    add[b * Cn + t] = a;
}

// K4: out = x + add broadcast; x from bf16 copy (BF) or fp32. grid (2, Bn*Cn), 256 thr.
template<bool BF>
__global__ void k_out(const float* __restrict__ x, const ushort_t* __restrict__ xb,
                      const float* __restrict__ add, float* __restrict__ out) {
    const int bc = blockIdx.y;
    const float a = add[bc];
    const int t = threadIdx.x;
    const size_t ebase = (size_t)bc * Ln + (size_t)blockIdx.x * 8192;
    v4f* xo = (v4f*)(out + ebase);
    if (BF) {
        const ush8* xi = (const ush8*)(xb + ebase);
        #pragma unroll
        for (int k = 0; k < 4; ++k) {
            ush8 h = xi[k * 256 + t];
            v4f o0 = {bf2f(h[0]) + a, bf2f(h[1]) + a, bf2f(h[2]) + a, bf2f(h[3]) + a};
            v4f o1 = {bf2f(h[4]) + a, bf2f(h[5]) + a, bf2f(h[6]) + a, bf2f(h[7]) + a};
            __builtin_nontemporal_store(o0, xo + (k * 256 + t) * 2);
            __builtin_nontemporal_store(o1, xo + (k * 256 + t) * 2 + 1);
        }
    } else {
        const float4* xi = (const float4*)(x + ebase);
        #pragma unroll
        for (int k = 0; k < 8; ++k) {
            float4 v = xi[k * 256 + t];
            v4f o = {v.x + a, v.y + a, v.z + a, v.w + a};
            __builtin_nontemporal_store(o, xo + k * 256 + t);
        }
    }
}

extern "C" void kernel_launch(void* const* d_in, const int* in_sizes, int n_in,
                              void* d_out, int out_size, void* d_ws, size_t ws_size,
                              hipStream_t stream) {
    const float* x      = (const float*)d_in[0];
    const float* w_mask = (const float*)d_in[1];
    const float* b_mask = (const float*)d_in[2];
    const float* w1     = (const float*)d_in[3];
    const float* b1     = (const float*)d_in[4];
    const float* ln_g   = (const float*)d_in[5];
    const float* ln_b   = (const float*)d_in[6];
    const float* w2     = (const float*)d_in[7];
    const float* b2     = (const float*)d_in[8];
    float* out = (float*)d_out;

    float* ws    = (float*)d_ws;
    float* e_ws  = ws;                                  // Bn*Ln = 262144 floats
    float* mz    = e_ws + (size_t)Bn * Ln;              // Bn*NCH*2 = 1024 floats
    float* ctx   = mz + (size_t)Bn * NCH * 2;           // Bn*Cn = 4096 floats
    float* add   = ctx + (size_t)Bn * Cn;               // Bn*Cn = 4096 floats
    ushort_t* xb = (ushort_t*)(add + (size_t)Bn * Cn);  // Bn*Cn*Ln bf16 = 128 MiB
    const size_t need = (size_t)(add + (size_t)Bn * Cn - ws) * 4
                      + (size_t)Bn * Cn * Ln * 2;
    const bool bf = ws_size >= need;

    if (bf) {
        k_pass1<true><<<dim3(NCH, Bn), 256, 0, stream>>>(x, w_mask, b_mask, e_ws, mz, xb);
        k_norm<<<Bn, 256, 0, stream>>>(e_ws, mz);
        k_ctx<true><<<Bn * Cn, 256, 0, stream>>>(x, xb, e_ws, ctx);
        k_mlp<<<Bn, 256, 0, stream>>>(ctx, w1, b1, ln_g, ln_b, w2, b2, add);
        k_out<true><<<dim3(2, Bn * Cn), 256, 0, stream>>>(x, xb, add, out);
    } else {
        k_pass1<false><<<dim3(NCH, Bn), 256, 0, stream>>>(x, w_mask, b_mask, e_ws, mz, xb);
        k_norm<<<Bn, 256, 0, stream>>>(e_ws, mz);
        k_ctx<false><<<Bn * Cn, 256, 0, stream>>>(x, xb, e_ws, ctx);
        k_mlp<<<Bn, 256, 0, stream>>>(ctx, w1, b1, ln_g, ln_b, w2, b2, add);
        k_out<false><<<dim3(2, Bn * Cn), 256, 0, stream>>>(x, xb, add, out);
    }
}

// Round 7
// 142.047 us; speedup vs baseline: 1.6789x; 1.6789x over previous
//
#include <hip/hip_runtime.h>
#include <math.h>

#define Bn 16
#define Cn 256
#define Ln 16384
#define Mn 64
#define LN_EPS 1e-5f
#define CHUNK 64
#define NCH (Ln / CHUNK)   // 256
#define XSTR 65            // LDS row stride (floats): 2-way bank aliasing only

typedef float v4f __attribute__((ext_vector_type(4)));

// K1: fused logits + chunk softmax + pooling, chunk staged in LDS.
// grid (NCH, Bn) = 4096 blocks, 256 threads, ~69 KB LDS -> 2 blocks/CU.
__global__ __launch_bounds__(256) void k_pool(
        const float* __restrict__ x, const float* __restrict__ w_mask,
        const float* __restrict__ b_mask,
        float* __restrict__ ctxU,   // [Bn][NCH][Cn]
        float* __restrict__ mz) {   // [Bn][NCH][2]
    const int ch = blockIdx.x, b = blockIdx.y;
    const int t = threadIdx.x;   // 256
    __shared__ float xs[Cn * XSTR];     // 66560 B
    __shared__ float wm_s[Cn];
    __shared__ float red2[4 * CHUNK];
    __shared__ float e_s[CHUNK];

    wm_s[t] = w_mask[t];

    // ---- stage: x[b][c][ch*64 .. +64) -> xs[c][l], float4 global loads ----
    const size_t xbase = (size_t)b * Cn * Ln + (size_t)ch * CHUNK;
    const int sub = t >> 4;        // row within group of 16
    const int f4 = t & 15;         // float4 index within row (l = 4*f4)
    #pragma unroll
    for (int r = 0; r < 16; ++r) {
        const int c = r * 16 + sub;
        float4 v = *(const float4*)(x + xbase + (size_t)c * Ln + 4 * f4);
        float* dst = xs + c * XSTR + 4 * f4;
        dst[0] = v.x; dst[1] = v.y; dst[2] = v.z; dst[3] = v.w;
    }
    __syncthreads();

    // ---- phase A: logits from LDS ----
    // wave wv computes partial over c in [wv*64, wv*64+64) for l = lane
    const int wv = t >> 6, lane = t & 63;
    {
        float p = 0.f;
        #pragma unroll 8
        for (int k = 0; k < 64; ++k) {
            const int c = wv * 64 + k;
            p += xs[c * XSTR + lane] * wm_s[c];
        }
        red2[wv * CHUNK + lane] = p;
    }
    __syncthreads();
    if (t < 64) {
        const float logit = red2[t] + red2[64 + t] + red2[128 + t] + red2[192 + t]
                          + b_mask[0];
        float m = logit;
        for (int off = 32; off; off >>= 1) m = fmaxf(m, __shfl_xor(m, off, 64));
        const float e = expf(logit - m);
        e_s[t] = e;
        float z = e;
        for (int off = 32; off; off >>= 1) z += __shfl_xor(z, off, 64);
        if (t == 0) {
            mz[(b * NCH + ch) * 2 + 0] = m;
            mz[(b * NCH + ch) * 2 + 1] = z;
        }
    }
    __syncthreads();

    // ---- phase B: thread t = channel c; no cross-lane reduction ----
    float acc = 0.f;
    #pragma unroll 8
    for (int l = 0; l < CHUNK; ++l)
        acc += xs[t * XSTR + l] * e_s[l];   // e_s[l]: broadcast (free)
    ctxU[((size_t)b * NCH + ch) * Cn + t] = acc;
}

// K2: flash combine over NCH chunks -> ctx, then tiny MLP -> add. grid Bn, 256 thr.
__global__ void k_comb_mlp(const float* __restrict__ ctxU, const float* __restrict__ mz,
                           const float* __restrict__ w1, const float* __restrict__ b1,
                           const float* __restrict__ ln_g, const float* __restrict__ ln_b,
                           const float* __restrict__ w2, const float* __restrict__ b2,
                           float* __restrict__ add) {
    const int b = blockIdx.x;
    const int t = threadIdx.x;   // 256 (== NCH)
    __shared__ float s_sc[NCH];
    __shared__ float s_red[8];
    __shared__ float ctx_s[Cn];
    __shared__ float h_s[Mn];

    // per-thread chunk t: compute global M, Z, then scale sc[t] = exp(m_t - M)/Z
    const float mt = mz[(b * NCH + t) * 2 + 0];
    const float zt = mz[(b * NCH + t) * 2 + 1];
    float M = mt;
    for (int off = 32; off; off >>= 1) M = fmaxf(M, __shfl_xor(M, off, 64));
    if ((t & 63) == 0) s_red[t >> 6] = M;
    __syncthreads();
    M = fmaxf(fmaxf(s_red[0], s_red[1]), fmaxf(s_red[2], s_red[3]));
    const float sc = expf(mt - M);
    float zw = zt * sc;
    for (int off = 32; off; off >>= 1) zw += __shfl_xor(zw, off, 64);
    if ((t & 63) == 0) s_red[4 + (t >> 6)] = zw;
    __syncthreads();
    const float Z = s_red[4] + s_red[5] + s_red[6] + s_red[7];
    s_sc[t] = sc / Z;
    __syncthreads();

    // ctx[c] = sum_ch ctxU[b][ch][c] * s_sc[ch]   (coalesced over t per ch)
    float s = 0.f;
    for (int chk = 0; chk < NCH; ++chk)
        s += ctxU[((size_t)b * NCH + chk) * Cn + t] * s_sc[chk];
    ctx_s[t] = s;
    __syncthreads();

    // h[m] = b1[m] + sum_c ctx[c]*w1[m][c]; 4 threads per m
    const int m4 = t >> 2, j = t & 3;
    float hp = 0.f;
    for (int c = j; c < Cn; c += 4) hp += ctx_s[c] * w1[m4 * Cn + c];
    hp += __shfl_xor(hp, 1, 64);
    hp += __shfl_xor(hp, 2, 64);
    if (j == 0) h_s[m4] = hp + b1[m4];
    __syncthreads();

    if (t < 64) {
        float h = h_s[t];
        float mu = h;
        for (int off = 32; off; off >>= 1) mu += __shfl_xor(mu, off, 64);
        mu *= (1.f / 64.f);
        const float d = h - mu;
        float var = d * d;
        for (int off = 32; off; off >>= 1) var += __shfl_xor(var, off, 64);
        var *= (1.f / 64.f);
        h = d * rsqrtf(var + LN_EPS) * ln_g[t] + ln_b[t];
        h_s[t] = fmaxf(h, 0.f);
    }
    __syncthreads();

    float a = b2[t];
    #pragma unroll
    for (int mm = 0; mm < Mn; ++mm) a += h_s[mm] * w2[t * Mn + mm];
    add[b * Cn + t] = a;
}

// K3: out = x + add broadcast. Nontemporal stores. grid (4, Bn*Cn), 256 thr.
__global__ void k_out(const float* __restrict__ x, const float* __restrict__ add,
                      float* __restrict__ out) {
    const int bc = blockIdx.y;
    const float a = add[bc];
    const size_t base = (size_t)bc * Ln + (size_t)blockIdx.x * 4096;
    const float4* xi = (const float4*)(x + base);
    v4f* xo = (v4f*)(out + base);
    const int t = threadIdx.x;
    #pragma unroll
    for (int k = 0; k < 4; ++k) {
        float4 v = xi[k * 256 + t];
        v4f o = {v.x + a, v.y + a, v.z + a, v.w + a};
        __builtin_nontemporal_store(o, xo + k * 256 + t);
    }
}

extern "C" void kernel_launch(void* const* d_in, const int* in_sizes, int n_in,
                              void* d_out, int out_size, void* d_ws, size_t ws_size,
                              hipStream_t stream) {
    const float* x      = (const float*)d_in[0];
    const float* w_mask = (const float*)d_in[1];
    const float* b_mask = (const float*)d_in[2];
    const float* w1     = (const float*)d_in[3];
    const float* b1     = (const float*)d_in[4];
    const float* ln_g   = (const float*)d_in[5];
    const float* ln_b   = (const float*)d_in[6];
    const float* w2     = (const float*)d_in[7];
    const float* b2     = (const float*)d_in[8];
    float* out = (float*)d_out;

    float* ws   = (float*)d_ws;
    float* ctxU = ws;                                  // Bn*NCH*Cn = 1M floats (4 MiB)
    float* mz   = ctxU + (size_t)Bn * NCH * Cn;        // Bn*NCH*2 = 8192 floats
    float* add  = mz + (size_t)Bn * NCH * 2;           // Bn*Cn = 4096 floats

    k_pool<<<dim3(NCH, Bn), 256, 0, stream>>>(x, w_mask, b_mask, ctxU, mz);
    k_comb_mlp<<<Bn, 256, 0, stream>>>(ctxU, mz, w1, b1, ln_g, ln_b, w2, b2, add);
    k_out<<<dim3(4, Bn * Cn), 256, 0, stream>>>(x, add, out);
}